// Round 8
// baseline (141.643 us; speedup 1.0000x reference)
//
#include <hip/hip_runtime.h>
#include <hip/hip_bf16.h>

// Problem constants
#define B    32
#define P    576     // 24*24 patches
#define D    768
#define K1   17      // K+1 prototypes
#define KFG  16
#define C    200
#define LN_EPS 1e-6f

typedef __attribute__((ext_vector_type(8))) short short8;   // 8 bf16 (4 VGPRs)
typedef __attribute__((ext_vector_type(4))) float f32x4;

// packed fp32x8 -> bf16x8 via v_cvt_pk_bf16_f32
__device__ inline short8 cvt8(float4 a, float4 b) {
    union { unsigned u[4]; short8 s; } r;
    union { __hip_bfloat162 h; unsigned u; } c;
    c.h = __float22bfloat162_rn(make_float2(a.x, a.y)); r.u[0] = c.u;
    c.h = __float22bfloat162_rn(make_float2(a.z, a.w)); r.u[1] = c.u;
    c.h = __float22bfloat162_rn(make_float2(b.x, b.y)); r.u[2] = c.u;
    c.h = __float22bfloat162_rn(make_float2(b.z, b.w)); r.u[3] = c.u;
    return r.s;
}
__device__ inline float sq8(float4 a, float4 b) {
    return a.x*a.x + a.y*a.y + a.z*a.z + a.w*a.w
         + b.x*b.x + b.y*b.y + b.z*b.z + b.w*b.w;
}

// ================= K1: dots (bf16 MFMA, K-split 4) + softmax =================
// grid (36 tiles, 32 b) x 256 (4 waves). Block = one 16-patch tile; wave wv owns
// K-range [wv*192, wv*192+192) = 6 MFMA steps. 4608 waves (~18/CU) for latency
// hiding. Also zero-inits v for k_pool's atomic accumulate (ws is poisoned each
// iter; kernel boundary orders init -> add).
// Session lessons: NO cross-block fences (round-1: +175 µs from L2 maintenance);
// memory-touching kernels need many blocks (round-4); monolithic fused phases
// lose to split kernels (rounds 4-5). Atomics are OK — fences are not (rounds 6-7).
__global__ __launch_bounds__(256) void k_dots(const float* __restrict__ x,
                                              const float* __restrict__ proto,
                                              float* __restrict__ A_out,
                                              float* __restrict__ apool,
                                              float* __restrict__ v) {
    __shared__ float scL[4 * 64 * 11];   // [wave][lane][acc0:4|acc1:4|sq0|sq6], stride 11
    const int tile = blockIdx.x, b = blockIdx.y;
    const int t = threadIdx.x, wv = t >> 6, lane = t & 63;
    const int n = lane & 15, kq = lane >> 4;
    const int p0 = tile * 16;

    // zero v (393216 floats over 1152 blocks x 256 threads, grid-stride, coalesced)
    for (int i = (b * 36 + tile) * 256 + t; i < B * KFG * D; i += 36 * B * 256)
        v[i] = 0.f;

    const float* arow = x     + ((size_t)(b * P + p0 + n)) * D + wv * 192 + kq * 8;
    const float* brow = proto + (size_t)n  * D + wv * 192 + kq * 8;
    const float* brw6 = proto + (size_t)16 * D + wv * 192 + kq * 8;

    f32x4 acc0 = {0.f, 0.f, 0.f, 0.f};   // protos 0..15, this K-quarter
    f32x4 acc1 = {0.f, 0.f, 0.f, 0.f};   // proto 16 (broadcast B)
    float sq0 = 0.f, sq6 = 0.f;          // psq partials (fp32-exact)

    #pragma unroll
    for (int s = 0; s < 6; ++s) {
        float4 a0 = *(const float4*)(arow + s * 32);
        float4 a1 = *(const float4*)(arow + s * 32 + 4);
        float4 b0 = *(const float4*)(brow + s * 32);
        float4 b1 = *(const float4*)(brow + s * 32 + 4);
        float4 c0 = *(const float4*)(brw6 + s * 32);
        float4 c1 = *(const float4*)(brw6 + s * 32 + 4);
        short8 A  = cvt8(a0, a1);
        short8 Bv = cvt8(b0, b1);
        short8 B6 = cvt8(c0, c1);
        sq0 += sq8(b0, b1);
        sq6 += sq8(c0, c1);
        acc0 = __builtin_amdgcn_mfma_f32_16x16x32_bf16(A, Bv, acc0, 0, 0, 0);
        acc1 = __builtin_amdgcn_mfma_f32_16x16x32_bf16(A, B6, acc1, 0, 0, 0);
    }
    // fold the 4 kq-quads (lanes n, n+16, n+32, n+48 share proto n)
    sq0 += __shfl_xor(sq0, 16, 64); sq0 += __shfl_xor(sq0, 32, 64);
    sq6 += __shfl_xor(sq6, 16, 64); sq6 += __shfl_xor(sq6, 32, 64);

    {
        float* s = scL + (wv * 64 + lane) * 11;
        #pragma unroll
        for (int r = 0; r < 4; ++r) { s[r] = acc0[r]; s[r + 4] = acc1[r]; }
        s[8] = sq0; s[9] = sq6;
    }
    __syncthreads();
    if (wv != 0) return;

    // ---- reduce 4 K-quarters (wave 0) ----
    float f0[4], f1[4]; float fsq0 = 0.f, fsq6 = 0.f;
    #pragma unroll
    for (int r = 0; r < 4; ++r) { f0[r] = 0.f; f1[r] = 0.f; }
    #pragma unroll
    for (int w = 0; w < 4; ++w) {
        const float* s = scL + (w * 64 + lane) * 11;
        #pragma unroll
        for (int r = 0; r < 4; ++r) { f0[r] += s[r]; f1[r] += s[r + 4]; }
        fsq0 += s[8]; fsq6 += s[9];
    }

    // ---- softmax per (kq, r) across n (xor 1,2,4,8 stays within quad) ----
    float a_[4], a16[4];
    #pragma unroll
    for (int r = 0; r < 4; ++r) {
        float l0  = 2.f * f0[r] - fsq0;
        float l16 = 2.f * f1[r] - fsq6;
        float mx = l0;
        #pragma unroll
        for (int o = 1; o < 16; o <<= 1) mx = fmaxf(mx, __shfl_xor(mx, o, 64));
        mx = fmaxf(mx, l16);
        float e0  = __expf(l0 - mx);
        float e16 = __expf(l16 - mx);
        float sum = e0;
        #pragma unroll
        for (int o = 1; o < 16; o <<= 1) sum += __shfl_xor(sum, o, 64);
        sum += e16;
        const float inv = 1.f / sum;
        a_[r]  = e0 * inv;
        a16[r] = e16 * inv;
    }

    *(float4*)(A_out + ((size_t)b * K1 + n) * P + p0 + kq * 4) =
        make_float4(a_[0], a_[1], a_[2], a_[3]);
    if (n == 0)
        *(float4*)(A_out + ((size_t)b * K1 + 16) * P + p0 + kq * 4) =
            make_float4(a16[0], a16[1], a16[2], a16[3]);

    const float invP = 1.f / (float)P;
    #pragma unroll
    for (int r = 0; r < 4; ++r)
        apool[((size_t)b * P + p0 + kq * 4 + r) * KFG + n] = a_[r] * invP;
}

// ================= K2: fp32 pooling; atomic-accumulate into final v =================
// grid (3 dchunk, 6 psplit of 96, 32 b) x 256; thread owns one d. ZERO LDS.
// x is L3-resident after k_dots; apool rows are blockIdx-uniform -> s_load_dwordx16.
// 16 atomicAdds/thread (coalesced across lanes, 6-way contention/address) replace
// the vpart store+reload round-trip (-15.7 MB traffic; v was zeroed by k_dots).
__global__ __launch_bounds__(256, 4) void k_pool(const float* __restrict__ x,
                                                 const float* __restrict__ apool,
                                                 float* __restrict__ v) {
    const int dc = blockIdx.x, psl = blockIdx.y, b = blockIdx.z;
    const int t = threadIdx.x;
    const int d = dc * 256 + t;

    const float* aw = apool + ((size_t)b * P + psl * 96) * KFG;   // uniform (blockIdx)
    const float* xp = x + ((size_t)b * P + psl * 96) * D + d;

    float acc[KFG];
    #pragma unroll
    for (int k = 0; k < KFG; ++k) acc[k] = 0.f;

    #pragma unroll 4
    for (int p = 0; p < 96; ++p) {
        float xv = xp[(size_t)p * D];
        f32x4 A0 = *(const f32x4*)(aw + p * 16);        // -> s_load_dwordx16
        f32x4 A1 = *(const f32x4*)(aw + p * 16 + 4);
        f32x4 A2 = *(const f32x4*)(aw + p * 16 + 8);
        f32x4 A3 = *(const f32x4*)(aw + p * 16 + 12);
        acc[0]  += A0[0] * xv; acc[1]  += A0[1] * xv; acc[2]  += A0[2] * xv; acc[3]  += A0[3] * xv;
        acc[4]  += A1[0] * xv; acc[5]  += A1[1] * xv; acc[6]  += A1[2] * xv; acc[7]  += A1[3] * xv;
        acc[8]  += A2[0] * xv; acc[9]  += A2[1] * xv; acc[10] += A2[2] * xv; acc[11] += A2[3] * xv;
        acc[12] += A3[0] * xv; acc[13] += A3[1] * xv; acc[14] += A3[2] * xv; acc[15] += A3[3] * xv;
    }
    float* o = v + ((size_t)b * KFG) * D + d;
    #pragma unroll
    for (int k = 0; k < KFG; ++k)
        atomicAdd(o + (size_t)k * D, acc[k]);
}

// ======== K3: LayerNorm on v; write vnorm + vT; init parts/agg bias ========
// grid (16 k, 32 b) x 256; thread owns 3 d's (3 loads now — v is pre-reduced).
// Tail threads pre-load bias into parts/agg so k_cls can atomic-combine (round 7).
__global__ __launch_bounds__(256) void k_ln(const float* __restrict__ v,
                                            const float* __restrict__ gamma,
                                            const float* __restrict__ beta,
                                            const float* __restrict__ bcls,
                                            float* __restrict__ vnorm_out,
                                            float* __restrict__ vT,
                                            float* __restrict__ parts,
                                            float* __restrict__ agg) {
    const int k = blockIdx.x, b = blockIdx.y, t = threadIdx.x;
    const int lane = t & 63, wv = t >> 6;

    float vv[3]; float s1 = 0.f, s2 = 0.f;
    #pragma unroll
    for (int j = 0; j < 3; ++j) {
        const int d = t + j * 256;
        float s = v[((size_t)b * KFG + k) * D + d];
        vv[j] = s; s1 += s; s2 += s * s;
    }
    #pragma unroll
    for (int o = 1; o < 64; o <<= 1) {
        s1 += __shfl_xor(s1, o, 64);
        s2 += __shfl_xor(s2, o, 64);
    }
    __shared__ float r1[4], r2[4];
    if (lane == 0) { r1[wv] = s1; r2[wv] = s2; }
    __syncthreads();
    s1 = r1[0] + r1[1] + r1[2] + r1[3];
    s2 = r2[0] + r2[1] + r2[2] + r2[3];

    const float mean = s1 * (1.f / (float)D);
    const float var  = s2 * (1.f / (float)D) - mean * mean;
    const float rs   = rsqrtf(var + LN_EPS);

    #pragma unroll
    for (int j = 0; j < 3; ++j) {
        const int d = t + j * 256;
        float vn = (vv[j] - mean) * rs * gamma[d] + beta[d];
        vnorm_out[((size_t)b * KFG + k) * D + d] = vn;
        vT[((size_t)b * D + d) * KFG + k] = vn;   // k-contiguous for k_cls s_loads
    }

    // bias pre-load for the atomic combine (independent of LN math above)
    if (t < C) {
        const float bc = bcls[t];
        parts[((size_t)b * KFG + k) * C + t] = bc;
        if (k == 0) agg[(size_t)b * C + t] = bc;
    }
}

// ===== K4: classifier partial GEMV; atomic-combine into parts/agg (no k_comb) =====
// grid (8 dq of 96 d, 32 b) x 256; thread = class c. dq=8 (96-iter loop) is the
// PROVEN config: the long independent-load loop is the latency hider (ILP);
// dq=16 regressed (round 2). Stores replaced by fire-and-forget global atomicAdd
// (8-way contention/address max); bias pre-loaded by k_ln (kernel-boundary order).
__global__ __launch_bounds__(256) void k_cls(const float* __restrict__ vT,
                                             const float* __restrict__ W,
                                             float* __restrict__ parts,
                                             float* __restrict__ agg) {
    const int dq = blockIdx.x, b = blockIdx.y;
    const int c = threadIdx.x;
    const int cc = c < C ? c : (C - 1);

    const float* vt = vT + ((size_t)b * D + dq * 96) * KFG;   // uniform (blockIdx)
    const float* Wp = W + (size_t)dq * 96 * C + cc;

    float acc[KFG];
    #pragma unroll
    for (int k = 0; k < KFG; ++k) acc[k] = 0.f;

    #pragma unroll 4
    for (int i = 0; i < 96; ++i) {
        float wl = Wp[(size_t)i * C];                 // coalesced across lanes
        f32x4 V0 = *(const f32x4*)(vt + i * 16);      // -> s_load_dwordx16
        f32x4 V1 = *(const f32x4*)(vt + i * 16 + 4);
        f32x4 V2 = *(const f32x4*)(vt + i * 16 + 8);
        f32x4 V3 = *(const f32x4*)(vt + i * 16 + 12);
        acc[0]  += V0[0] * wl; acc[1]  += V0[1] * wl; acc[2]  += V0[2] * wl; acc[3]  += V0[3] * wl;
        acc[4]  += V1[0] * wl; acc[5]  += V1[1] * wl; acc[6]  += V1[2] * wl; acc[7]  += V1[3] * wl;
        acc[8]  += V2[0] * wl; acc[9]  += V2[1] * wl; acc[10] += V2[2] * wl; acc[11] += V2[3] * wl;
        acc[12] += V3[0] * wl; acc[13] += V3[1] * wl; acc[14] += V3[2] * wl; acc[15] += V3[3] * wl;
    }
    if (c < C) {
        float* o = parts + ((size_t)b * KFG) * C + c;
        float s_agg = 0.f;
        #pragma unroll
        for (int k = 0; k < KFG; ++k) {
            atomicAdd(o + (size_t)k * C, acc[k]);
            s_agg += acc[k];
        }
        atomicAdd(agg + (size_t)b * C + c, s_agg * (1.f / (float)KFG));
    }
}

extern "C" void kernel_launch(void* const* d_in, const int* in_sizes, int n_in,
                              void* d_out, int out_size, void* d_ws, size_t ws_size,
                              hipStream_t stream) {
    const float* x     = (const float*)d_in[0];   // (32,24,24,768)
    const float* proto = (const float*)d_in[1];   // (17,768)
    const float* gamma = (const float*)d_in[2];   // (768)
    const float* beta  = (const float*)d_in[3];   // (768)
    const float* W     = (const float*)d_in[4];   // (768,200)
    const float* bcls  = (const float*)d_in[5];   // (200)

    float* out = (float*)d_out;
    float* A_out     = out;                       // 32*17*576   = 313344
    float* vnorm_out = out + 313344;              // 32*16*768   = 393216
    float* parts_out = out + 706560;              // 32*16*200   = 102400
    float* agg_out   = out + 808960;              // 32*200      = 6400

    float* ws = (float*)d_ws;
    float* apool = ws;                             // 32*576*16   = 294912
    float* v     = apool + 294912;                 // 32*16*768   = 393216
    float* vT    = v + 393216;                     // 32*768*16   = 393216

    hipLaunchKernelGGL(k_dots, dim3(36, B),   dim3(256), 0, stream, x, proto, A_out, apool, v);
    hipLaunchKernelGGL(k_pool, dim3(3, 6, B), dim3(256), 0, stream, x, apool, v);
    hipLaunchKernelGGL(k_ln,   dim3(KFG, B),  dim3(256), 0, stream, v, gamma, beta, bcls,
                       vnorm_out, vT, parts_out, agg_out);
    hipLaunchKernelGGL(k_cls,  dim3(8, B),    dim3(256), 0, stream, vT, W, parts_out, agg_out);
}

// Round 9
// 136.855 us; speedup vs baseline: 1.0350x; 1.0350x over previous
//
#include <hip/hip_runtime.h>
#include <hip/hip_bf16.h>

// Problem constants
#define B    32
#define P    576     // 24*24 patches
#define D    768
#define K1   17      // K+1 prototypes
#define KFG  16
#define C    200
#define LN_EPS 1e-6f

typedef __attribute__((ext_vector_type(8))) short short8;   // 8 bf16 (4 VGPRs)
typedef __attribute__((ext_vector_type(4))) float f32x4;

// packed fp32x8 -> bf16x8 via v_cvt_pk_bf16_f32
__device__ inline short8 cvt8(float4 a, float4 b) {
    union { unsigned u[4]; short8 s; } r;
    union { __hip_bfloat162 h; unsigned u; } c;
    c.h = __float22bfloat162_rn(make_float2(a.x, a.y)); r.u[0] = c.u;
    c.h = __float22bfloat162_rn(make_float2(a.z, a.w)); r.u[1] = c.u;
    c.h = __float22bfloat162_rn(make_float2(b.x, b.y)); r.u[2] = c.u;
    c.h = __float22bfloat162_rn(make_float2(b.z, b.w)); r.u[3] = c.u;
    return r.s;
}
__device__ inline float sq8(float4 a, float4 b) {
    return a.x*a.x + a.y*a.y + a.z*a.z + a.w*a.w
         + b.x*b.x + b.y*b.y + b.z*b.z + b.w*b.w;
}

// ================= K1: dots (bf16 MFMA, K-split 4) + softmax =================
// grid (36 tiles, 32 b) x 256 (4 waves). Block = one 16-patch tile; wave wv owns
// K-range [wv*192, wv*192+192) = 6 MFMA steps. 4608 waves (~18/CU) for latency
// hiding. psq accumulated in-loop from fp32 protos. LDS 11.3 KB.
// Session lessons: NO cross-block fences (round-1: +175 µs from L2 maintenance);
// memory-touching kernels need many blocks (round-4); monolithic fused phases
// lose to split kernels (rounds 4-5). Atomics into OUTPUTS are OK (round-7);
// atomics to shortcut intra-pipeline round-trips are not worth it (round-8:
// off-critical-path traffic is free; added serial init + contention isn't).
__global__ __launch_bounds__(256) void k_dots(const float* __restrict__ x,
                                              const float* __restrict__ proto,
                                              float* __restrict__ A_out,
                                              float* __restrict__ apool) {
    __shared__ float scL[4 * 64 * 11];   // [wave][lane][acc0:4|acc1:4|sq0|sq6], stride 11
    const int tile = blockIdx.x, b = blockIdx.y;
    const int t = threadIdx.x, wv = t >> 6, lane = t & 63;
    const int n = lane & 15, kq = lane >> 4;
    const int p0 = tile * 16;

    const float* arow = x     + ((size_t)(b * P + p0 + n)) * D + wv * 192 + kq * 8;
    const float* brow = proto + (size_t)n  * D + wv * 192 + kq * 8;
    const float* brw6 = proto + (size_t)16 * D + wv * 192 + kq * 8;

    f32x4 acc0 = {0.f, 0.f, 0.f, 0.f};   // protos 0..15, this K-quarter
    f32x4 acc1 = {0.f, 0.f, 0.f, 0.f};   // proto 16 (broadcast B)
    float sq0 = 0.f, sq6 = 0.f;          // psq partials (fp32-exact)

    #pragma unroll
    for (int s = 0; s < 6; ++s) {
        float4 a0 = *(const float4*)(arow + s * 32);
        float4 a1 = *(const float4*)(arow + s * 32 + 4);
        float4 b0 = *(const float4*)(brow + s * 32);
        float4 b1 = *(const float4*)(brow + s * 32 + 4);
        float4 c0 = *(const float4*)(brw6 + s * 32);
        float4 c1 = *(const float4*)(brw6 + s * 32 + 4);
        short8 A  = cvt8(a0, a1);
        short8 Bv = cvt8(b0, b1);
        short8 B6 = cvt8(c0, c1);
        sq0 += sq8(b0, b1);
        sq6 += sq8(c0, c1);
        acc0 = __builtin_amdgcn_mfma_f32_16x16x32_bf16(A, Bv, acc0, 0, 0, 0);
        acc1 = __builtin_amdgcn_mfma_f32_16x16x32_bf16(A, B6, acc1, 0, 0, 0);
    }
    // fold the 4 kq-quads (lanes n, n+16, n+32, n+48 share proto n)
    sq0 += __shfl_xor(sq0, 16, 64); sq0 += __shfl_xor(sq0, 32, 64);
    sq6 += __shfl_xor(sq6, 16, 64); sq6 += __shfl_xor(sq6, 32, 64);

    {
        float* s = scL + (wv * 64 + lane) * 11;
        #pragma unroll
        for (int r = 0; r < 4; ++r) { s[r] = acc0[r]; s[r + 4] = acc1[r]; }
        s[8] = sq0; s[9] = sq6;
    }
    __syncthreads();
    if (wv != 0) return;

    // ---- reduce 4 K-quarters (wave 0) ----
    float f0[4], f1[4]; float fsq0 = 0.f, fsq6 = 0.f;
    #pragma unroll
    for (int r = 0; r < 4; ++r) { f0[r] = 0.f; f1[r] = 0.f; }
    #pragma unroll
    for (int w = 0; w < 4; ++w) {
        const float* s = scL + (w * 64 + lane) * 11;
        #pragma unroll
        for (int r = 0; r < 4; ++r) { f0[r] += s[r]; f1[r] += s[r + 4]; }
        fsq0 += s[8]; fsq6 += s[9];
    }

    // ---- softmax per (kq, r) across n (xor 1,2,4,8 stays within quad) ----
    float a_[4], a16[4];
    #pragma unroll
    for (int r = 0; r < 4; ++r) {
        float l0  = 2.f * f0[r] - fsq0;
        float l16 = 2.f * f1[r] - fsq6;
        float mx = l0;
        #pragma unroll
        for (int o = 1; o < 16; o <<= 1) mx = fmaxf(mx, __shfl_xor(mx, o, 64));
        mx = fmaxf(mx, l16);
        float e0  = __expf(l0 - mx);
        float e16 = __expf(l16 - mx);
        float sum = e0;
        #pragma unroll
        for (int o = 1; o < 16; o <<= 1) sum += __shfl_xor(sum, o, 64);
        sum += e16;
        const float inv = 1.f / sum;
        a_[r]  = e0 * inv;
        a16[r] = e16 * inv;
    }

    *(float4*)(A_out + ((size_t)b * K1 + n) * P + p0 + kq * 4) =
        make_float4(a_[0], a_[1], a_[2], a_[3]);
    if (n == 0)
        *(float4*)(A_out + ((size_t)b * K1 + 16) * P + p0 + kq * 4) =
            make_float4(a16[0], a16[1], a16[2], a16[3]);

    const float invP = 1.f / (float)P;
    #pragma unroll
    for (int r = 0; r < 4; ++r)
        apool[((size_t)b * P + p0 + kq * 4 + r) * KFG + n] = a_[r] * invP;
}

// ================= K2: fp32 pooling; a-rows via provably-uniform s_loads =================
// grid (3 dchunk, 6 psplit of 96, 32 b) x 256; thread owns one d. ZERO LDS.
// x is L3-resident after k_dots; apool rows are blockIdx-uniform -> s_load_dwordx16.
__global__ __launch_bounds__(256, 4) void k_pool(const float* __restrict__ x,
                                                 const float* __restrict__ apool,
                                                 float* __restrict__ vpart) {
    const int dc = blockIdx.x, psl = blockIdx.y, b = blockIdx.z;
    const int t = threadIdx.x;
    const int d = dc * 256 + t;

    const float* aw = apool + ((size_t)b * P + psl * 96) * KFG;   // uniform (blockIdx)
    const float* xp = x + ((size_t)b * P + psl * 96) * D + d;

    float acc[KFG];
    #pragma unroll
    for (int k = 0; k < KFG; ++k) acc[k] = 0.f;

    #pragma unroll 4
    for (int p = 0; p < 96; ++p) {
        float xv = xp[(size_t)p * D];
        f32x4 A0 = *(const f32x4*)(aw + p * 16);        // -> s_load_dwordx16
        f32x4 A1 = *(const f32x4*)(aw + p * 16 + 4);
        f32x4 A2 = *(const f32x4*)(aw + p * 16 + 8);
        f32x4 A3 = *(const f32x4*)(aw + p * 16 + 12);
        acc[0]  += A0[0] * xv; acc[1]  += A0[1] * xv; acc[2]  += A0[2] * xv; acc[3]  += A0[3] * xv;
        acc[4]  += A1[0] * xv; acc[5]  += A1[1] * xv; acc[6]  += A1[2] * xv; acc[7]  += A1[3] * xv;
        acc[8]  += A2[0] * xv; acc[9]  += A2[1] * xv; acc[10] += A2[2] * xv; acc[11] += A2[3] * xv;
        acc[12] += A3[0] * xv; acc[13] += A3[1] * xv; acc[14] += A3[2] * xv; acc[15] += A3[3] * xv;
    }
    float* o = vpart + ((size_t)(psl * B + b) * KFG) * D + d;
    #pragma unroll
    for (int k = 0; k < KFG; ++k) o[(size_t)k * D] = acc[k];
}

// ======== K3: reduce 6 p-splits + LayerNorm; write vnorm + vT; init parts/agg bias ========
// grid (16 k, 32 b) x 256; thread owns 3 d's. Tail threads also pre-load the bias
// into parts (this block's (b,k) row) and agg (k==0), so k_cls can atomicAdd
// partials directly and k_comb disappears.
__global__ __launch_bounds__(256) void k_ln(const float* __restrict__ vpart,
                                            const float* __restrict__ gamma,
                                            const float* __restrict__ beta,
                                            const float* __restrict__ bcls,
                                            float* __restrict__ vnorm_out,
                                            float* __restrict__ vT,
                                            float* __restrict__ parts,
                                            float* __restrict__ agg) {
    const int k = blockIdx.x, b = blockIdx.y, t = threadIdx.x;
    const int lane = t & 63, wv = t >> 6;

    float v[3]; float s1 = 0.f, s2 = 0.f;
    #pragma unroll
    for (int j = 0; j < 3; ++j) {
        const int d = t + j * 256;
        float s = 0.f;
        #pragma unroll
        for (int psl = 0; psl < 6; ++psl)
            s += vpart[((size_t)(psl * B + b) * KFG + k) * D + d];
        v[j] = s; s1 += s; s2 += s * s;
    }
    #pragma unroll
    for (int o = 1; o < 64; o <<= 1) {
        s1 += __shfl_xor(s1, o, 64);
        s2 += __shfl_xor(s2, o, 64);
    }
    __shared__ float r1[4], r2[4];
    if (lane == 0) { r1[wv] = s1; r2[wv] = s2; }
    __syncthreads();
    s1 = r1[0] + r1[1] + r1[2] + r1[3];
    s2 = r2[0] + r2[1] + r2[2] + r2[3];

    const float mean = s1 * (1.f / (float)D);
    const float var  = s2 * (1.f / (float)D) - mean * mean;
    const float rs   = rsqrtf(var + LN_EPS);

    #pragma unroll
    for (int j = 0; j < 3; ++j) {
        const int d = t + j * 256;
        float vn = (v[j] - mean) * rs * gamma[d] + beta[d];
        vnorm_out[((size_t)b * KFG + k) * D + d] = vn;
        vT[((size_t)b * D + d) * KFG + k] = vn;   // k-contiguous for k_cls s_loads
    }

    // bias pre-load for the atomic combine (independent of LN math above)
    if (t < C) {
        const float bc = bcls[t];
        parts[((size_t)b * KFG + k) * C + t] = bc;
        if (k == 0) agg[(size_t)b * C + t] = bc;
    }
}

// ===== K4: classifier partial GEMV; atomic-combine into parts/agg (no k_comb) =====
// grid (8 dq of 96 d, 32 b) x 256; thread = class c. dq=8 (96-iter loop) is the
// PROVEN config: the long independent-load loop is the latency hider (ILP);
// dq=16 regressed (round 2). Stores replaced by fire-and-forget global atomicAdd
// (8-way contention/address max); bias pre-loaded by k_ln (kernel-boundary order).
__global__ __launch_bounds__(256) void k_cls(const float* __restrict__ vT,
                                             const float* __restrict__ W,
                                             float* __restrict__ parts,
                                             float* __restrict__ agg) {
    const int dq = blockIdx.x, b = blockIdx.y;
    const int c = threadIdx.x;
    const int cc = c < C ? c : (C - 1);

    const float* vt = vT + ((size_t)b * D + dq * 96) * KFG;   // uniform (blockIdx)
    const float* Wp = W + (size_t)dq * 96 * C + cc;

    float acc[KFG];
    #pragma unroll
    for (int k = 0; k < KFG; ++k) acc[k] = 0.f;

    #pragma unroll 4
    for (int i = 0; i < 96; ++i) {
        float wl = Wp[(size_t)i * C];                 // coalesced across lanes
        f32x4 V0 = *(const f32x4*)(vt + i * 16);      // -> s_load_dwordx16
        f32x4 V1 = *(const f32x4*)(vt + i * 16 + 4);
        f32x4 V2 = *(const f32x4*)(vt + i * 16 + 8);
        f32x4 V3 = *(const f32x4*)(vt + i * 16 + 12);
        acc[0]  += V0[0] * wl; acc[1]  += V0[1] * wl; acc[2]  += V0[2] * wl; acc[3]  += V0[3] * wl;
        acc[4]  += V1[0] * wl; acc[5]  += V1[1] * wl; acc[6]  += V1[2] * wl; acc[7]  += V1[3] * wl;
        acc[8]  += V2[0] * wl; acc[9]  += V2[1] * wl; acc[10] += V2[2] * wl; acc[11] += V2[3] * wl;
        acc[12] += V3[0] * wl; acc[13] += V3[1] * wl; acc[14] += V3[2] * wl; acc[15] += V3[3] * wl;
    }
    if (c < C) {
        float* o = parts + ((size_t)b * KFG) * C + c;
        float s_agg = 0.f;
        #pragma unroll
        for (int k = 0; k < KFG; ++k) {
            atomicAdd(o + (size_t)k * C, acc[k]);
            s_agg += acc[k];
        }
        atomicAdd(agg + (size_t)b * C + c, s_agg * (1.f / (float)KFG));
    }
}

extern "C" void kernel_launch(void* const* d_in, const int* in_sizes, int n_in,
                              void* d_out, int out_size, void* d_ws, size_t ws_size,
                              hipStream_t stream) {
    const float* x     = (const float*)d_in[0];   // (32,24,24,768)
    const float* proto = (const float*)d_in[1];   // (17,768)
    const float* gamma = (const float*)d_in[2];   // (768)
    const float* beta  = (const float*)d_in[3];   // (768)
    const float* W     = (const float*)d_in[4];   // (768,200)
    const float* bcls  = (const float*)d_in[5];   // (200)

    float* out = (float*)d_out;
    float* A_out     = out;                       // 32*17*576   = 313344
    float* vnorm_out = out + 313344;              // 32*16*768   = 393216
    float* parts_out = out + 706560;              // 32*16*200   = 102400
    float* agg_out   = out + 808960;              // 32*200      = 6400

    float* ws = (float*)d_ws;
    float* apool = ws;                             // 32*576*16    = 294912
    float* vpart = apool + 294912;                 // 6*32*16*768  = 2359296
    float* vT    = vpart + 2359296;                // 32*768*16    = 393216

    hipLaunchKernelGGL(k_dots, dim3(36, B),   dim3(256), 0, stream, x, proto, A_out, apool);
    hipLaunchKernelGGL(k_pool, dim3(3, 6, B), dim3(256), 0, stream, x, apool, vpart);
    hipLaunchKernelGGL(k_ln,   dim3(KFG, B),  dim3(256), 0, stream, vpart, gamma, beta, bcls,
                       vnorm_out, vT, parts_out, agg_out);
    hipLaunchKernelGGL(k_cls,  dim3(8, B),    dim3(256), 0, stream, vT, W, parts_out, agg_out);
}